// Round 2
// baseline (37.796 us; speedup 1.0000x reference)
//
#include <hip/hip_runtime.h>
#include <float.h>

// Problem constants (fixed by the reference setup_inputs()).
#define N_BATCH 4
#define P1 8192
#define P2 8192
#define D 3

#define CHUNK 256                  // targets staged in LDS per block
#define NCHUNK (P2 / CHUNK)        // 32
#define RSRC 8                     // source points per thread
#define TPB 256
#define SRC_PER_BLK (TPB * RSRC)   // 2048
#define NSRCBLK (P1 / SRC_PER_BLK) // 4
#define NMIN (N_BATCH * P1)        // 32768 per-source mins

// Main pass: each block computes, for its 2048 sources and its 256-target
// chunk, the partial min over targets of (y^2 - 2*x.y). Race-free store to
// ws[chunk][source] — no atomics, no init kernel needed.
__global__ __launch_bounds__(TPB) void chamfer_main(
        const float* __restrict__ src,
        const float* __restrict__ tgt,
        float* __restrict__ ws) {
    const int bid = blockIdx.x;
    const int c   = bid % NCHUNK;
    const int sb  = (bid / NCHUNK) % NSRCBLK;
    const int n   = bid / (NCHUNK * NSRCBLK);
    const int t   = threadIdx.x;

    __shared__ float4 sT[CHUNK];   // (-2*y0, -2*y1, -2*y2, y.y) per target

    {
        const int j = c * CHUNK + t;
        const float* p = tgt + ((size_t)n * P2 + j) * D;
        const float y0 = p[0], y1 = p[1], y2 = p[2];
        sT[t] = make_float4(-2.0f * y0, -2.0f * y1, -2.0f * y2,
                            y0 * y0 + y1 * y1 + y2 * y2);
    }
    __syncthreads();

    float x0[RSRC], x1[RSRC], x2[RSRC], m[RSRC];
#pragma unroll
    for (int i = 0; i < RSRC; ++i) {
        const int s = sb * SRC_PER_BLK + i * TPB + t;
        const float* p = src + ((size_t)n * P1 + s) * D;
        x0[i] = p[0]; x1[i] = p[1]; x2[i] = p[2];
        m[i] = FLT_MAX;
    }

    // 2 targets/iter: 6 FMA + 1 min3 per 2 pairs = 3.5 VALU/pair.
#pragma unroll 2
    for (int j = 0; j < CHUNK; j += 2) {
        const float4 ya = sT[j];
        const float4 yb = sT[j + 1];
#pragma unroll
        for (int i = 0; i < RSRC; ++i) {
            float da = __builtin_fmaf(x0[i], ya.x, ya.w);
            da = __builtin_fmaf(x1[i], ya.y, da);
            da = __builtin_fmaf(x2[i], ya.z, da);
            float db = __builtin_fmaf(x0[i], yb.x, yb.w);
            db = __builtin_fmaf(x1[i], yb.y, db);
            db = __builtin_fmaf(x2[i], yb.z, db);
            m[i] = fminf(fminf(m[i], da), db);  // -> v_min3_f32
        }
    }

    // Race-free partial-min store (coalesced per i).
#pragma unroll
    for (int i = 0; i < RSRC; ++i) {
        const int s = n * P1 + sb * SRC_PER_BLK + i * TPB + t;
        ws[(size_t)c * NMIN + s] = m[i];
    }
}

// Reduce: per source, min over 32 chunk-partials, add x^2, clamp, sum.
__global__ __launch_bounds__(TPB) void chamfer_reduce(
        const float* __restrict__ ws,
        const float* __restrict__ src,
        float* __restrict__ out) {
    const int gid = blockIdx.x * TPB + threadIdx.x;  // source id, 0..NMIN-1

    float v = ws[gid];
#pragma unroll
    for (int c = 1; c < NCHUNK; ++c)
        v = fminf(v, ws[(size_t)c * NMIN + gid]);

    const float* p = src + (size_t)gid * D;
    const float xs = p[0] * p[0] + p[1] * p[1] + p[2] * p[2];
    v = fmaxf(v + xs, 0.0f);

    // wave64 + block sum
#pragma unroll
    for (int off = 32; off > 0; off >>= 1)
        v += __shfl_down(v, off, 64);
    __shared__ float sred[TPB / 64];
    const int lane = threadIdx.x & 63;
    const int w    = threadIdx.x >> 6;
    if (lane == 0) sred[w] = v;
    __syncthreads();
    if (threadIdx.x == 0) {
        float s = 0.0f;
#pragma unroll
        for (int i = 0; i < TPB / 64; ++i) s += sred[i];
        atomicAdd(out, s * (1.0f / N_BATCH));  // batch_reduction='mean'
    }
}

extern "C" void kernel_launch(void* const* d_in, const int* in_sizes, int n_in,
                              void* d_out, int out_size, void* d_ws, size_t ws_size,
                              hipStream_t stream) {
    const float* src = (const float*)d_in[0];  // (4, 8192, 3) f32
    const float* tgt = (const float*)d_in[1];  // (4, 8192, 3) f32
    float* out = (float*)d_out;                // scalar f32
    float* ws  = (float*)d_ws;                 // 32 * 32768 * 4B = 4 MB

    hipMemsetAsync(out, 0, sizeof(float), stream);

    const int nblocks = N_BATCH * NSRCBLK * NCHUNK;  // 512
    chamfer_main<<<nblocks, TPB, 0, stream>>>(src, tgt, ws);

    chamfer_reduce<<<NMIN / TPB, TPB, 0, stream>>>(ws, src, out);
}

// Round 3
// 36.989 us; speedup vs baseline: 1.0218x; 1.0218x over previous
//
#include <hip/hip_runtime.h>
#include <float.h>

// Problem constants (fixed by the reference setup_inputs()).
#define N_BATCH 4
#define P1 8192
#define P2 8192
#define D 3

#define CHUNK 256                  // targets staged in LDS per block
#define NCHUNK (P2 / CHUNK)        // 32
#define RSRC 4                     // source points per thread
#define TPB 256
#define SRC_PER_BLK (TPB * RSRC)   // 1024
#define NSRCBLK (P1 / SRC_PER_BLK) // 8
#define NMIN (N_BATCH * P1)        // 32768 per-source mins

#define TPB_R 128                  // reduce kernel block size

// Main pass: block (n, sb, c) computes, for its 1024 sources and its
// 256-target chunk, min over targets of (y^2 - 2*x.y). Race-free store to
// ws[chunk][source] — no atomics, no init kernel.
__global__ __launch_bounds__(TPB) void chamfer_main(
        const float* __restrict__ src,
        const float* __restrict__ tgt,
        float* __restrict__ ws) {
    const int bid = blockIdx.x;
    const int c   = bid % NCHUNK;
    const int sb  = (bid / NCHUNK) % NSRCBLK;
    const int n   = bid / (NCHUNK * NSRCBLK);
    const int t   = threadIdx.x;

    __shared__ float4 sT[CHUNK];   // (-2*y0, -2*y1, -2*y2, y.y) per target

    {
        const int j = c * CHUNK + t;
        const float* p = tgt + ((size_t)n * P2 + j) * D;
        const float y0 = p[0], y1 = p[1], y2 = p[2];
        sT[t] = make_float4(-2.0f * y0, -2.0f * y1, -2.0f * y2,
                            y0 * y0 + y1 * y1 + y2 * y2);
    }
    __syncthreads();

    float x0[RSRC], x1[RSRC], x2[RSRC], m[RSRC];
#pragma unroll
    for (int i = 0; i < RSRC; ++i) {
        const int s = sb * SRC_PER_BLK + i * TPB + t;
        const float* p = src + ((size_t)n * P1 + s) * D;
        x0[i] = p[0]; x1[i] = p[1]; x2[i] = p[2];
        m[i] = FLT_MAX;
    }

    // Groups of 8 targets: 8 independent broadcast ds_read_b128 clustered,
    // then 4 sources x (6 FMA + 1 min3) x 4 pairs = 56 VALU per group.
    // All y[] indices are compile-time after unroll -> registers.
#pragma unroll 2
    for (int jb = 0; jb < CHUNK; jb += 8) {
        float4 y[8];
#pragma unroll
        for (int k = 0; k < 8; ++k) y[k] = sT[jb + k];
#pragma unroll
        for (int k = 0; k < 8; k += 2) {
            const float4 ya = y[k];
            const float4 yb = y[k + 1];
#pragma unroll
            for (int i = 0; i < RSRC; ++i) {
                float da = __builtin_fmaf(x0[i], ya.x, ya.w);
                da = __builtin_fmaf(x1[i], ya.y, da);
                da = __builtin_fmaf(x2[i], ya.z, da);
                float db = __builtin_fmaf(x0[i], yb.x, yb.w);
                db = __builtin_fmaf(x1[i], yb.y, db);
                db = __builtin_fmaf(x2[i], yb.z, db);
                m[i] = fminf(fminf(m[i], da), db);  // -> v_min3_f32
            }
        }
    }

    // Race-free partial-min store (coalesced per i).
#pragma unroll
    for (int i = 0; i < RSRC; ++i) {
        const int s = n * P1 + sb * SRC_PER_BLK + i * TPB + t;
        ws[(size_t)c * NMIN + s] = m[i];
    }
}

// Reduce: per source, min over 32 chunk-partials (tree for ILP), add x^2,
// clamp, block-sum, one atomicAdd per block.
__global__ __launch_bounds__(TPB_R) void chamfer_reduce(
        const float* __restrict__ ws,
        const float* __restrict__ src,
        float* __restrict__ out) {
    const int gid = blockIdx.x * TPB_R + threadIdx.x;  // source id

    float v[NCHUNK];
#pragma unroll
    for (int c = 0; c < NCHUNK; ++c)
        v[c] = ws[(size_t)c * NMIN + gid];
#pragma unroll
    for (int s = NCHUNK / 2; s > 0; s >>= 1)
#pragma unroll
        for (int c = 0; c < s; ++c)
            v[c] = fminf(v[c], v[c + s]);

    const float* p = src + (size_t)gid * D;
    const float xs = p[0] * p[0] + p[1] * p[1] + p[2] * p[2];
    float r = fmaxf(v[0] + xs, 0.0f);

#pragma unroll
    for (int off = 32; off > 0; off >>= 1)
        r += __shfl_down(r, off, 64);
    __shared__ float sred[TPB_R / 64];
    const int lane = threadIdx.x & 63;
    const int w    = threadIdx.x >> 6;
    if (lane == 0) sred[w] = r;
    __syncthreads();
    if (threadIdx.x == 0) {
        float s = 0.0f;
#pragma unroll
        for (int i = 0; i < TPB_R / 64; ++i) s += sred[i];
        atomicAdd(out, s * (1.0f / N_BATCH));  // batch_reduction='mean'
    }
}

extern "C" void kernel_launch(void* const* d_in, const int* in_sizes, int n_in,
                              void* d_out, int out_size, void* d_ws, size_t ws_size,
                              hipStream_t stream) {
    const float* src = (const float*)d_in[0];  // (4, 8192, 3) f32
    const float* tgt = (const float*)d_in[1];  // (4, 8192, 3) f32
    float* out = (float*)d_out;                // scalar f32
    float* ws  = (float*)d_ws;                 // 32 * 32768 * 4B = 4 MB

    hipMemsetAsync(out, 0, sizeof(float), stream);

    const int nblocks = N_BATCH * NSRCBLK * NCHUNK;  // 4*8*32 = 1024
    chamfer_main<<<nblocks, TPB, 0, stream>>>(src, tgt, ws);

    chamfer_reduce<<<NMIN / TPB_R, TPB_R, 0, stream>>>(ws, src, out);
}

// Round 4
// 33.909 us; speedup vs baseline: 1.1146x; 1.0908x over previous
//
#include <hip/hip_runtime.h>
#include <float.h>

// Problem constants (fixed by the reference setup_inputs()).
#define N_BATCH 4
#define P1 8192
#define P2 8192
#define D 3

#define CHUNK 128                  // targets staged in LDS per block
#define NCHUNK (P2 / CHUNK)        // 64
#define RSRC 8                     // source points per thread
#define TPB 256
#define SRC_PER_BLK (TPB * RSRC)   // 2048
#define NSRCBLK (P1 / SRC_PER_BLK) // 4
#define NMIN (N_BATCH * P1)        // 32768 per-source mins

#define TPB_R 256                  // reduce kernel block size

// Main pass: block (n, sb, c) computes, for its 2048 sources and its
// 128-target chunk, min over targets of (y^2 - 2*x.y). Race-free store to
// ws[chunk][source]. Block 0 also zeroes the output scalar (safe: the
// reduce kernel is stream-ordered after this one).
__global__ __launch_bounds__(TPB) void chamfer_main(
        const float* __restrict__ src,
        const float* __restrict__ tgt,
        float* __restrict__ ws,
        float* __restrict__ out) {
    const int bid = blockIdx.x;
    const int c   = bid % NCHUNK;
    const int sb  = (bid / NCHUNK) % NSRCBLK;
    const int n   = bid / (NCHUNK * NSRCBLK);
    const int t   = threadIdx.x;

    if (bid == 0 && t == 0) out[0] = 0.0f;

    __shared__ float4 sT[CHUNK];   // (-2*y0, -2*y1, -2*y2, y.y) per target

    if (t < CHUNK) {
        const int j = c * CHUNK + t;
        const float* p = tgt + ((size_t)n * P2 + j) * D;
        const float y0 = p[0], y1 = p[1], y2 = p[2];
        sT[t] = make_float4(-2.0f * y0, -2.0f * y1, -2.0f * y2,
                            y0 * y0 + y1 * y1 + y2 * y2);
    }
    __syncthreads();

    float x0[RSRC], x1[RSRC], x2[RSRC], m[RSRC];
#pragma unroll
    for (int i = 0; i < RSRC; ++i) {
        const int s = sb * SRC_PER_BLK + i * TPB + t;
        const float* p = src + ((size_t)n * P1 + s) * D;
        x0[i] = p[0]; x1[i] = p[1]; x2[i] = p[2];
        m[i] = FLT_MAX;
    }

    // Groups of 8 targets: 8 clustered broadcast ds_read_b128, then
    // 8 targets x 8 sources x 3.5 VALU = 224 VALU per group
    // (0.125 ds_read per pair -> LDS pipe under the VALU pipe).
#pragma unroll 2
    for (int jb = 0; jb < CHUNK; jb += 8) {
        float4 y[8];
#pragma unroll
        for (int k = 0; k < 8; ++k) y[k] = sT[jb + k];
#pragma unroll
        for (int k = 0; k < 8; k += 2) {
            const float4 ya = y[k];
            const float4 yb = y[k + 1];
#pragma unroll
            for (int i = 0; i < RSRC; ++i) {
                float da = __builtin_fmaf(x0[i], ya.x, ya.w);
                da = __builtin_fmaf(x1[i], ya.y, da);
                da = __builtin_fmaf(x2[i], ya.z, da);
                float db = __builtin_fmaf(x0[i], yb.x, yb.w);
                db = __builtin_fmaf(x1[i], yb.y, db);
                db = __builtin_fmaf(x2[i], yb.z, db);
                m[i] = fminf(fminf(m[i], da), db);  // -> v_min3_f32
            }
        }
    }

    // Race-free partial-min store (coalesced per i).
#pragma unroll
    for (int i = 0; i < RSRC; ++i) {
        const int s = n * P1 + sb * SRC_PER_BLK + i * TPB + t;
        ws[(size_t)c * NMIN + s] = m[i];
    }
}

// Reduce: per source, min over 64 chunk-partials (tree for ILP), add x^2,
// clamp, block-sum, one atomicAdd per block.
__global__ __launch_bounds__(TPB_R) void chamfer_reduce(
        const float* __restrict__ ws,
        const float* __restrict__ src,
        float* __restrict__ out) {
    const int gid = blockIdx.x * TPB_R + threadIdx.x;  // source id

    float v[NCHUNK];
#pragma unroll
    for (int c = 0; c < NCHUNK; ++c)
        v[c] = ws[(size_t)c * NMIN + gid];
#pragma unroll
    for (int s = NCHUNK / 2; s > 0; s >>= 1)
#pragma unroll
        for (int c = 0; c < s; ++c)
            v[c] = fminf(v[c], v[c + s]);

    const float* p = src + (size_t)gid * D;
    const float xs = p[0] * p[0] + p[1] * p[1] + p[2] * p[2];
    float r = fmaxf(v[0] + xs, 0.0f);

#pragma unroll
    for (int off = 32; off > 0; off >>= 1)
        r += __shfl_down(r, off, 64);
    __shared__ float sred[TPB_R / 64];
    const int lane = threadIdx.x & 63;
    const int w    = threadIdx.x >> 6;
    if (lane == 0) sred[w] = r;
    __syncthreads();
    if (threadIdx.x == 0) {
        float s = 0.0f;
#pragma unroll
        for (int i = 0; i < TPB_R / 64; ++i) s += sred[i];
        atomicAdd(out, s * (1.0f / N_BATCH));  // batch_reduction='mean'
    }
}

extern "C" void kernel_launch(void* const* d_in, const int* in_sizes, int n_in,
                              void* d_out, int out_size, void* d_ws, size_t ws_size,
                              hipStream_t stream) {
    const float* src = (const float*)d_in[0];  // (4, 8192, 3) f32
    const float* tgt = (const float*)d_in[1];  // (4, 8192, 3) f32
    float* out = (float*)d_out;                // scalar f32
    float* ws  = (float*)d_ws;                 // 64 * 32768 * 4B = 8 MB

    const int nblocks = N_BATCH * NSRCBLK * NCHUNK;  // 4*4*64 = 1024
    chamfer_main<<<nblocks, TPB, 0, stream>>>(src, tgt, ws, out);

    chamfer_reduce<<<NMIN / TPB_R, TPB_R, 0, stream>>>(ws, src, out);
}